// Round 2
// baseline (887.618 us; speedup 1.0000x reference)
//
#include <hip/hip_runtime.h>
#include <hip/hip_bf16.h>

typedef __attribute__((ext_vector_type(8))) short bf16x8;
typedef __attribute__((ext_vector_type(4))) float f32x4;

#define CIN 64
#define COUT 64
#define NK 64
#define SLABK 16             // kernels per z-slab
#define SLABCOL 1024         // SLABK * COUT
#define EPSV 1e-5f
#define ENC_NEG_INF 0x007FFFFFu

__device__ __forceinline__ unsigned encf(float f) {
    unsigned b = __float_as_uint(f);
    return (b & 0x80000000u) ? ~b : (b | 0x80000000u);
}
__device__ __forceinline__ float decf(unsigned u) {
    unsigned b = (u & 0x80000000u) ? (u & 0x7FFFFFFFu) : ~u;
    return __uint_as_float(b);
}

// ---------------------------------------------------------------------------
// Kernel 0: transpose weight [k][c][d] fp32 -> wt [k][d][c] bf16
// ---------------------------------------------------------------------------
__global__ __launch_bounds__(256) void transpose_w_kernel(
    const float* __restrict__ w, __hip_bfloat16* __restrict__ wt) {
    int i = blockIdx.x * 256 + threadIdx.x;          // 64*64*64 = 262144 total
    int k = i >> 12, r = i & 4095, d = r >> 6, c = r & 63;
    wt[i] = __float2bfloat16(w[(k << 12) + (c << 6) + d]);
}

// ---------------------------------------------------------------------------
// Kernel 1: slab GEMM  xwc[n][kk][d] = sum_c x[n][c]*W[k0+kk][c][d], kk<16
// Block: 256 thr (4 waves), M-tile = 128 rows.
// ---------------------------------------------------------------------------
__global__ __launch_bounds__(256) void gemm_xw_kernel(
    const float* __restrict__ x, const __hip_bfloat16* __restrict__ wt,
    __hip_bfloat16* __restrict__ xwc, int nNodes, int k0) {
    __shared__ __attribute__((aligned(16))) __hip_bfloat16 As[128 * 72];
    __shared__ __attribute__((aligned(16))) __hip_bfloat16 Bs[64 * 72];

    const int tid  = threadIdx.x;
    const int wave = tid >> 6, lane = tid & 63;
    const int quad = lane >> 4, l16 = lane & 15;
    const int row0 = blockIdx.x * 128;

    // stage A tile: 128 rows x 64 cols, fp32 -> bf16
    for (int i = 0; i < 32; ++i) {
        int idx = tid + i * 256;
        int r = idx >> 6, c = idx & 63;
        float v = (row0 + r < nNodes) ? x[(size_t)(row0 + r) * CIN + c] : 0.f;
        As[r * 72 + c] = __float2bfloat16(v);
    }

    for (int kk = 0; kk < SLABK; ++kk) {
        int k = k0 + kk;
        // stage B^T tile: Bs[d][c] = W[k][c][d] (wt is pre-transposed)
        for (int i = 0; i < 16; ++i) {
            int idx = tid + i * 256;
            Bs[(idx >> 6) * 72 + (idx & 63)] = wt[(size_t)k * 4096 + idx];
        }
        __syncthreads();

        f32x4 acc[2][4] = {};
        for (int ks = 0; ks < 2; ++ks) {
            int kb = ks * 32 + quad * 8;   // element offset within K dim
            bf16x8 afrag[2], bfrag[4];
            for (int mi = 0; mi < 2; ++mi)
                afrag[mi] = *(const bf16x8*)&As[(wave * 32 + mi * 16 + l16) * 72 + kb];
            for (int ni = 0; ni < 4; ++ni)
                bfrag[ni] = *(const bf16x8*)&Bs[(ni * 16 + l16) * 72 + kb];
            for (int mi = 0; mi < 2; ++mi)
                for (int ni = 0; ni < 4; ++ni)
                    acc[mi][ni] = __builtin_amdgcn_mfma_f32_16x16x32_bf16(
                        afrag[mi], bfrag[ni], acc[mi][ni], 0, 0, 0);
        }
        // C/D layout: col = lane&15, row = quad*4 + reg
        for (int mi = 0; mi < 2; ++mi)
            for (int ni = 0; ni < 4; ++ni)
                for (int r = 0; r < 4; ++r) {
                    int m = row0 + wave * 32 + mi * 16 + quad * 4 + r;
                    if (m < nNodes)
                        xwc[(size_t)m * SLABCOL + kk * 64 + ni * 16 + l16] =
                            __float2bfloat16(acc[mi][ni][r]);
                }
        __syncthreads();
    }
}

// ---------------------------------------------------------------------------
// Kernel 2: per-edge spline gather for one z-slab + scatter-add
// One wave per edge, lane = output channel. Edge active iff l2==slab (weight
// 1-t2) or l2==slab-1 (weight t2); 4 xy-corners gathered from the slab.
// ---------------------------------------------------------------------------
__global__ __launch_bounds__(256) void edge_kernel(
    const int* __restrict__ ei, const float* __restrict__ ea,
    const __hip_bfloat16* __restrict__ xwc,
    float* __restrict__ agg, float* __restrict__ cnt,
    int E, int slab, int doCnt) {
    int gwave  = (blockIdx.x * blockDim.x + threadIdx.x) >> 6;
    int nwaves = (gridDim.x * blockDim.x) >> 6;
    int lane   = threadIdx.x & 63;

    for (int e = gwave; e < E; e += nwaves) {
        int dst = ei[E + e];
        if (doCnt && lane == 0) atomicAdd(&cnt[dst], 1.f);

        float f2 = ea[e * 3 + 2] * 3.f;
        float l2 = fminf(fmaxf(floorf(f2), 0.f), 2.f);
        int l2i = (int)l2;
        if (l2i != slab && l2i != slab - 1) continue;   // wave-uniform skip
        float t2 = f2 - l2;
        float zw = (l2i == slab) ? (1.f - t2) : t2;

        int src = ei[e];
        float f0 = ea[e * 3 + 0] * 3.f;
        float f1 = ea[e * 3 + 1] * 3.f;
        float l0 = fminf(fmaxf(floorf(f0), 0.f), 2.f);
        float l1 = fminf(fmaxf(floorf(f1), 0.f), 2.f);
        float t0 = f0 - l0, t1 = f1 - l1;
        int base = (int)l0 + 4 * (int)l1;

        const __hip_bfloat16* p = xwc + (size_t)src * SLABCOL + base * 64 + lane;
        float acc = (1.f - t0) * (1.f - t1) * __bfloat162float(p[0])
                  + t0 * (1.f - t1)         * __bfloat162float(p[64])
                  + (1.f - t0) * t1         * __bfloat162float(p[256])
                  + t0 * t1                 * __bfloat162float(p[320]);
        atomicAdd(&agg[(size_t)dst * COUT + lane], acc * zw);
    }
}

// ---------------------------------------------------------------------------
// Kernel 3: h = elu(agg/max(cnt,1) + x@root + bias); accumulate BN sums
// ---------------------------------------------------------------------------
__global__ __launch_bounds__(256) void node_kernel(
    const float* __restrict__ x, const float* __restrict__ agg,
    const float* __restrict__ cnt, const float* __restrict__ root,
    const float* __restrict__ bias, float* __restrict__ h,
    float* __restrict__ gstat, int nNodes) {
    __shared__ float rootS[4096];
    __shared__ float red[8][64];
    int tid = threadIdx.x, wave = tid >> 6, lane = tid & 63;

    for (int i = tid; i < 4096; i += 256) rootS[i] = root[i];
    __syncthreads();

    float s = 0.f, s2 = 0.f;
    int n0 = blockIdx.x * 64 + wave * 16;
    for (int j = 0; j < 16; ++j) {
        int n = n0 + j;
        if (n >= nNodes) break;
        float xv  = x[(size_t)n * CIN + lane];
        float acc = bias[lane] + agg[(size_t)n * COUT + lane] / fmaxf(cnt[n], 1.f);
        for (int c = 0; c < 64; ++c)
            acc += __shfl(xv, c, 64) * rootS[c * 64 + lane];
        float hv = acc > 0.f ? acc : expm1f(acc);
        h[(size_t)n * COUT + lane] = hv;
        s += hv; s2 += hv * hv;
    }
    red[wave][lane] = s;
    red[4 + wave][lane] = s2;
    __syncthreads();
    if (tid < 64) {
        atomicAdd(&gstat[tid], red[0][tid] + red[1][tid] + red[2][tid] + red[3][tid]);
    } else if (tid < 128) {
        int d = tid - 64;
        atomicAdd(&gstat[64 + d], red[4][d] + red[5][d] + red[6][d] + red[7][d]);
    }
}

// ---------------------------------------------------------------------------
// Kernel 4: finalize BN scale/shift (1 block, 64 threads)
// ---------------------------------------------------------------------------
__global__ void stats_kernel(const float* __restrict__ gamma,
                             const float* __restrict__ beta,
                             float* __restrict__ gstat, int nNodes) {
    int d = threadIdx.x;
    float invn = 1.f / (float)nNodes;
    float mean = gstat[d] * invn;
    float var  = gstat[64 + d] * invn - mean * mean;
    float sc   = gamma[d] * rsqrtf(var + EPSV);
    gstat[128 + d] = sc;
    gstat[192 + d] = beta[d] - mean * sc;
}

// ---------------------------------------------------------------------------
// Kernel 5: init pooled output to encoded(-inf)
// ---------------------------------------------------------------------------
__global__ __launch_bounds__(256) void initpool_kernel(unsigned* __restrict__ out, int total) {
    int i = blockIdx.x * 256 + threadIdx.x;
    if (i < total) out[i] = ENC_NEG_INF;
}

// ---------------------------------------------------------------------------
// Kernel 6: normalize + voxel max-pool via monotone-uint atomicMax
// ---------------------------------------------------------------------------
__global__ __launch_bounds__(256) void pool_kernel(
    const float* __restrict__ h, const float* __restrict__ pos,
    const int* __restrict__ batch, const float* __restrict__ gstat,
    unsigned* __restrict__ out, int nNodes) {
    int gid = blockIdx.x * 256 + threadIdx.x;
    int n = gid >> 6, d = gid & 63;
    if (n >= nNodes) return;
    float v = h[gid] * gstat[128 + d] + gstat[192 + d];
    int v0 = min(max((int)floorf(pos[n * 3 + 0] * (1.f / 32.f)), 0), 7);
    int v1 = min(max((int)floorf(pos[n * 3 + 1] * (1.f / 32.f)), 0), 7);
    int v2 = min(max((int)floorf(pos[n * 3 + 2] * (1.f / 32.f)), 0), 7);
    int cl = batch[n] * 512 + v0 * 64 + v1 * 8 + v2;
    atomicMax(&out[cl * 64 + d], encf(v));
}

// ---------------------------------------------------------------------------
// Kernel 7: decode uint -> float, empty voxel -> 0
// ---------------------------------------------------------------------------
__global__ __launch_bounds__(256) void decode_kernel(unsigned* __restrict__ out, int total) {
    int i = blockIdx.x * 256 + threadIdx.x;
    if (i >= total) return;
    float f = decf(out[i]);
    if (!isfinite(f)) f = 0.f;
    ((float*)out)[i] = f;
}

// ---------------------------------------------------------------------------
extern "C" void kernel_launch(void* const* d_in, const int* in_sizes, int n_in,
                              void* d_out, int out_size, void* d_ws, size_t ws_size,
                              hipStream_t stream) {
    const float* x     = (const float*)d_in[0];
    const int*   ei    = (const int*)d_in[1];
    const float* ea    = (const float*)d_in[2];
    const float* pos   = (const float*)d_in[3];
    const int*   batch = (const int*)d_in[4];
    const float* w     = (const float*)d_in[5];
    const float* root  = (const float*)d_in[6];
    const float* bias  = (const float*)d_in[7];
    const float* gamma = (const float*)d_in[8];
    const float* beta  = (const float*)d_in[9];

    const int N = in_sizes[0] / CIN;     // 50000
    const int E = in_sizes[1] / 2;       // 800000

    // workspace carve-up (~116 MB total; h aliases the dead xwc buffer)
    char* ws = (char*)d_ws;
    size_t off = 0;
    auto carve = [&](size_t bytes) -> char* {
        char* p = ws + off;
        off = (off + bytes + 255) & ~(size_t)255;
        return p;
    };
    __hip_bfloat16* xwc = (__hip_bfloat16*)carve((size_t)N * SLABCOL * 2);  // 102.4 MB
    __hip_bfloat16* wt  = (__hip_bfloat16*)carve((size_t)NK * CIN * COUT * 2);
    float*          agg = (float*)carve((size_t)N * COUT * 4);
    float*          cnt = (float*)carve((size_t)N * 4);
    float*          gst = (float*)carve(256 * 4);
    float*          h   = (float*)xwc;   // reuse: xwc dead after last edge pass

    hipMemsetAsync(agg, 0, (size_t)N * COUT * 4, stream);
    hipMemsetAsync(cnt, 0, (size_t)N * 4, stream);
    hipMemsetAsync(gst, 0, 256 * 4, stream);

    transpose_w_kernel<<<(NK * CIN * COUT) / 256, 256, 0, stream>>>(w, wt);

    const int ggrid = (N + 127) / 128;
    for (int slab = 0; slab < 4; ++slab) {
        gemm_xw_kernel<<<ggrid, 256, 0, stream>>>(x, wt, xwc, N, slab * SLABK);
        edge_kernel<<<4096, 256, 0, stream>>>(ei, ea, xwc, agg, cnt, E, slab,
                                              slab == 0 ? 1 : 0);
    }

    node_kernel<<<(N + 63) / 64, 256, 0, stream>>>(x, agg, cnt, root, bias, h, gst, N);

    stats_kernel<<<1, 64, 0, stream>>>(gamma, beta, gst, N);

    initpool_kernel<<<(out_size + 255) / 256, 256, 0, stream>>>((unsigned*)d_out, out_size);

    pool_kernel<<<((size_t)N * COUT + 255) / 256, 256, 0, stream>>>(
        h, pos, batch, gst, (unsigned*)d_out, N);

    decode_kernel<<<(out_size + 255) / 256, 256, 0, stream>>>((unsigned*)d_out, out_size);
}

// Round 3
// 649.102 us; speedup vs baseline: 1.3675x; 1.3675x over previous
//
#include <hip/hip_runtime.h>
#include <hip/hip_bf16.h>

typedef __attribute__((ext_vector_type(8))) short bf16x8;
typedef __attribute__((ext_vector_type(4))) float f32x4;

#define CIN 64
#define COUT 64
#define NK 64
#define SLABK 16             // kernels per z-slab
#define SLABCOL 1024         // SLABK * COUT
#define EPSV 1e-5f
#define ENC_NEG_INF 0x007FFFFFu

__device__ __forceinline__ unsigned encf(float f) {
    unsigned b = __float_as_uint(f);
    return (b & 0x80000000u) ? ~b : (b | 0x80000000u);
}
__device__ __forceinline__ float decf(unsigned u) {
    unsigned b = (u & 0x80000000u) ? (u & 0x7FFFFFFFu) : ~u;
    return __uint_as_float(b);
}

// ---------------------------------------------------------------------------
// Kernel 0: transpose weight [k][c][d] fp32 -> wt [k][d][c] bf16
// ---------------------------------------------------------------------------
__global__ __launch_bounds__(256) void transpose_w_kernel(
    const float* __restrict__ w, __hip_bfloat16* __restrict__ wt) {
    int i = blockIdx.x * 256 + threadIdx.x;          // 262144 total
    int k = i >> 12, r = i & 4095, d = r >> 6, c = r & 63;
    wt[i] = __float2bfloat16(w[(k << 12) + (c << 6) + d]);
}

// ---------------------------------------------------------------------------
// CSR build: histogram -> scan -> scatter packed edge records
// record: x = src | base<<17 | l2i<<21 ; y = t0 | t1<<16 (16b fixed) ; z = t2
// ---------------------------------------------------------------------------
__global__ __launch_bounds__(256) void hist_kernel(
    const int* __restrict__ ei, int* __restrict__ deg, int E) {
    int e = blockIdx.x * 256 + threadIdx.x;
    if (e < E) atomicAdd(&deg[ei[E + e]], 1);
}

__global__ __launch_bounds__(1024) void scanA_kernel(
    const int* __restrict__ deg, int* __restrict__ psum, int n) {
    __shared__ int s[1024];
    int i = blockIdx.x * 1024 + threadIdx.x;
    s[threadIdx.x] = (i < n) ? deg[i] : 0;
    __syncthreads();
    for (int st = 512; st > 0; st >>= 1) {
        if (threadIdx.x < st) s[threadIdx.x] += s[threadIdx.x + st];
        __syncthreads();
    }
    if (threadIdx.x == 0) psum[blockIdx.x] = s[0];
}

__global__ void scanB_kernel(int* __restrict__ psum, int nb,
                             int* __restrict__ off, int n) {
    if (threadIdx.x == 0) {
        int run = 0;
        for (int b = 0; b < nb; ++b) { int v = psum[b]; psum[b] = run; run += v; }
        off[n] = run;
    }
}

__global__ __launch_bounds__(1024) void scanC_kernel(
    const int* __restrict__ deg, const int* __restrict__ psum,
    int* __restrict__ off, int* __restrict__ cur, int n) {
    __shared__ int s[1024];
    int tid = threadIdx.x, i = blockIdx.x * 1024 + tid;
    int v = (i < n) ? deg[i] : 0;
    s[tid] = v;
    for (int st = 1; st < 1024; st <<= 1) {
        __syncthreads();
        int t = (tid >= st) ? s[tid - st] : 0;
        __syncthreads();
        s[tid] += t;
    }
    __syncthreads();
    int excl = s[tid] - v + psum[blockIdx.x];
    if (i < n) { off[i] = excl; cur[i] = excl; }
}

__global__ __launch_bounds__(256) void scatter_kernel(
    const int* __restrict__ ei, const float* __restrict__ ea,
    int* __restrict__ cur, uint3* __restrict__ rec, int E) {
    int e = blockIdx.x * 256 + threadIdx.x;
    if (e >= E) return;
    int src = ei[e], dst = ei[E + e];
    float f0 = ea[e * 3 + 0] * 3.f;
    float f1 = ea[e * 3 + 1] * 3.f;
    float f2 = ea[e * 3 + 2] * 3.f;
    float l0 = fminf(fmaxf(floorf(f0), 0.f), 2.f);
    float l1 = fminf(fmaxf(floorf(f1), 0.f), 2.f);
    float l2 = fminf(fmaxf(floorf(f2), 0.f), 2.f);
    unsigned q0 = (unsigned)((f0 - l0) * 65536.f);
    unsigned q1 = (unsigned)((f1 - l1) * 65536.f);
    unsigned q2 = (unsigned)((f2 - l2) * 65536.f);
    int base = (int)l0 + 4 * (int)l1;
    uint3 r;
    r.x = (unsigned)src | ((unsigned)base << 17) | ((unsigned)(int)l2 << 21);
    r.y = q0 | (q1 << 16);
    r.z = q2;
    int pos = atomicAdd(&cur[dst], 1);
    rec[pos] = r;
}

// ---------------------------------------------------------------------------
// Kernel 1: slab GEMM  xwc[n][kk][d] = sum_c x[n][c]*W[k0+kk][c][d], kk<16
// ---------------------------------------------------------------------------
__global__ __launch_bounds__(256) void gemm_xw_kernel(
    const float* __restrict__ x, const __hip_bfloat16* __restrict__ wt,
    __hip_bfloat16* __restrict__ xwc, int nNodes, int k0) {
    __shared__ __attribute__((aligned(16))) __hip_bfloat16 As[128 * 72];
    __shared__ __attribute__((aligned(16))) __hip_bfloat16 Bs[64 * 72];

    const int tid  = threadIdx.x;
    const int wave = tid >> 6, lane = tid & 63;
    const int quad = lane >> 4, l16 = lane & 15;
    const int row0 = blockIdx.x * 128;

    for (int i = 0; i < 32; ++i) {
        int idx = tid + i * 256;
        int r = idx >> 6, c = idx & 63;
        float v = (row0 + r < nNodes) ? x[(size_t)(row0 + r) * CIN + c] : 0.f;
        As[r * 72 + c] = __float2bfloat16(v);
    }

    for (int kk = 0; kk < SLABK; ++kk) {
        int k = k0 + kk;
        for (int i = 0; i < 16; ++i) {
            int idx = tid + i * 256;
            Bs[(idx >> 6) * 72 + (idx & 63)] = wt[(size_t)k * 4096 + idx];
        }
        __syncthreads();

        f32x4 acc[2][4] = {};
        for (int ks = 0; ks < 2; ++ks) {
            int kb = ks * 32 + quad * 8;
            bf16x8 afrag[2], bfrag[4];
            for (int mi = 0; mi < 2; ++mi)
                afrag[mi] = *(const bf16x8*)&As[(wave * 32 + mi * 16 + l16) * 72 + kb];
            for (int ni = 0; ni < 4; ++ni)
                bfrag[ni] = *(const bf16x8*)&Bs[(ni * 16 + l16) * 72 + kb];
            for (int mi = 0; mi < 2; ++mi)
                for (int ni = 0; ni < 4; ++ni)
                    acc[mi][ni] = __builtin_amdgcn_mfma_f32_16x16x32_bf16(
                        afrag[mi], bfrag[ni], acc[mi][ni], 0, 0, 0);
        }
        for (int mi = 0; mi < 2; ++mi)
            for (int ni = 0; ni < 4; ++ni)
                for (int r = 0; r < 4; ++r) {
                    int m = row0 + wave * 32 + mi * 16 + quad * 4 + r;
                    if (m < nNodes)
                        xwc[(size_t)m * SLABCOL + kk * 64 + ni * 16 + l16] =
                            __float2bfloat16(acc[mi][ni][r]);
                }
        __syncthreads();
    }
}

// ---------------------------------------------------------------------------
// Kernel 2: per-dst aggregation for one z-slab. One wave per dst node,
// lane = channel. No atomics: wave exclusively owns agg row.
// ---------------------------------------------------------------------------
__global__ __launch_bounds__(256) void agg_kernel(
    const uint3* __restrict__ rec, const int* __restrict__ off,
    const __hip_bfloat16* __restrict__ xwc, float* __restrict__ agg,
    int nNodes, int slab) {
    int dst  = (blockIdx.x * 256 + threadIdx.x) >> 6;
    int lane = threadIdx.x & 63;
    if (dst >= nNodes) return;

    int s0 = __builtin_amdgcn_readfirstlane(off[dst]);
    int e0 = __builtin_amdgcn_readfirstlane(off[dst + 1]);

    float acc = 0.f;
    auto contrib = [&](uint3 r) {
        int l2i = (int)((r.x >> 21) & 3u);
        int d = l2i - slab;
        if (d != 0 && d != -1) return;               // wave-uniform skip
        float t2 = (float)(r.z & 0xffffu) * (1.f / 65536.f);
        float zw = (d == 0) ? 1.f - t2 : t2;
        int src  = (int)(r.x & 0x1ffffu);
        int base = (int)((r.x >> 17) & 15u);
        float t0 = (float)(r.y & 0xffffu) * (1.f / 65536.f);
        float t1 = (float)(r.y >> 16) * (1.f / 65536.f);
        float u0 = 1.f - t0, u1 = 1.f - t1;
        const __hip_bfloat16* p = xwc + (size_t)src * SLABCOL + base * 64 + lane;
        acc += zw * (u0 * u1 * __bfloat162float(p[0])
                   + t0 * u1 * __bfloat162float(p[64])
                   + u0 * t1 * __bfloat162float(p[256])
                   + t0 * t1 * __bfloat162float(p[320]));
    };

    int j = s0;
    while (j + 1 < e0) {                 // 2-edge unroll for gather MLP
        uint3 r0 = rec[j];
        uint3 r1 = rec[j + 1];
        j += 2;
        contrib(r0);
        contrib(r1);
    }
    if (j < e0) contrib(rec[j]);

    float* dp = &agg[(size_t)dst * COUT + lane];
    if (slab == 0) *dp = acc;
    else           *dp += acc;
}

// ---------------------------------------------------------------------------
// Kernel 3: h = elu(agg/max(deg,1) + x@root + bias); accumulate BN sums
// ---------------------------------------------------------------------------
__global__ __launch_bounds__(256) void node_kernel(
    const float* __restrict__ x, const float* __restrict__ agg,
    const int* __restrict__ deg, const float* __restrict__ root,
    const float* __restrict__ bias, float* __restrict__ h,
    float* __restrict__ gstat, int nNodes) {
    __shared__ float rootS[4096];
    __shared__ float red[8][64];
    int tid = threadIdx.x, wave = tid >> 6, lane = tid & 63;

    for (int i = tid; i < 4096; i += 256) rootS[i] = root[i];
    __syncthreads();

    float s = 0.f, s2 = 0.f;
    int n0 = blockIdx.x * 64 + wave * 16;
    for (int j = 0; j < 16; ++j) {
        int n = n0 + j;
        if (n >= nNodes) break;
        float xv  = x[(size_t)n * CIN + lane];
        float acc = bias[lane] + agg[(size_t)n * COUT + lane] /
                    fmaxf((float)deg[n], 1.f);
        for (int c = 0; c < 64; ++c)
            acc += __shfl(xv, c, 64) * rootS[c * 64 + lane];
        float hv = acc > 0.f ? acc : expm1f(acc);
        h[(size_t)n * COUT + lane] = hv;
        s += hv; s2 += hv * hv;
    }
    red[wave][lane] = s;
    red[4 + wave][lane] = s2;
    __syncthreads();
    if (tid < 64) {
        atomicAdd(&gstat[tid], red[0][tid] + red[1][tid] + red[2][tid] + red[3][tid]);
    } else if (tid < 128) {
        int d = tid - 64;
        atomicAdd(&gstat[64 + d], red[4][d] + red[5][d] + red[6][d] + red[7][d]);
    }
}

// ---------------------------------------------------------------------------
// Kernel 4: finalize BN scale/shift
// ---------------------------------------------------------------------------
__global__ void stats_kernel(const float* __restrict__ gamma,
                             const float* __restrict__ beta,
                             float* __restrict__ gstat, int nNodes) {
    int d = threadIdx.x;
    float invn = 1.f / (float)nNodes;
    float mean = gstat[d] * invn;
    float var  = gstat[64 + d] * invn - mean * mean;
    float sc   = gamma[d] * rsqrtf(var + EPSV);
    gstat[128 + d] = sc;
    gstat[192 + d] = beta[d] - mean * sc;
}

// ---------------------------------------------------------------------------
__global__ __launch_bounds__(256) void initpool_kernel(unsigned* __restrict__ out, int total) {
    int i = blockIdx.x * 256 + threadIdx.x;
    if (i < total) out[i] = ENC_NEG_INF;
}

__global__ __launch_bounds__(256) void pool_kernel(
    const float* __restrict__ h, const float* __restrict__ pos,
    const int* __restrict__ batch, const float* __restrict__ gstat,
    unsigned* __restrict__ out, int nNodes) {
    int gid = blockIdx.x * 256 + threadIdx.x;
    int n = gid >> 6, d = gid & 63;
    if (n >= nNodes) return;
    float v = h[gid] * gstat[128 + d] + gstat[192 + d];
    int v0 = min(max((int)floorf(pos[n * 3 + 0] * (1.f / 32.f)), 0), 7);
    int v1 = min(max((int)floorf(pos[n * 3 + 1] * (1.f / 32.f)), 0), 7);
    int v2 = min(max((int)floorf(pos[n * 3 + 2] * (1.f / 32.f)), 0), 7);
    int cl = batch[n] * 512 + v0 * 64 + v1 * 8 + v2;
    atomicMax(&out[cl * 64 + d], encf(v));
}

__global__ __launch_bounds__(256) void decode_kernel(unsigned* __restrict__ out, int total) {
    int i = blockIdx.x * 256 + threadIdx.x;
    if (i >= total) return;
    float f = decf(out[i]);
    if (!isfinite(f)) f = 0.f;
    ((float*)out)[i] = f;
}

// ---------------------------------------------------------------------------
extern "C" void kernel_launch(void* const* d_in, const int* in_sizes, int n_in,
                              void* d_out, int out_size, void* d_ws, size_t ws_size,
                              hipStream_t stream) {
    const float* x     = (const float*)d_in[0];
    const int*   ei    = (const int*)d_in[1];
    const float* ea    = (const float*)d_in[2];
    const float* pos   = (const float*)d_in[3];
    const int*   batch = (const int*)d_in[4];
    const float* w     = (const float*)d_in[5];
    const float* root  = (const float*)d_in[6];
    const float* bias  = (const float*)d_in[7];
    const float* gamma = (const float*)d_in[8];
    const float* beta  = (const float*)d_in[9];

    const int N = in_sizes[0] / CIN;     // 50000
    const int E = in_sizes[1] / 2;       // 800000

    // workspace carve-up (~126 MB; h aliases the dead xwc buffer)
    char* ws = (char*)d_ws;
    size_t off_b = 0;
    auto carve = [&](size_t bytes) -> char* {
        char* p = ws + off_b;
        off_b = (off_b + bytes + 255) & ~(size_t)255;
        return p;
    };
    __hip_bfloat16* xwc = (__hip_bfloat16*)carve((size_t)N * SLABCOL * 2);  // 102.4 MB
    __hip_bfloat16* wt  = (__hip_bfloat16*)carve((size_t)NK * CIN * COUT * 2);
    float*          agg = (float*)carve((size_t)N * COUT * 4);              // 12.8 MB
    int*            deg = (int*)carve((size_t)N * 4);
    int*            off = (int*)carve((size_t)(N + 1) * 4);
    int*            cur = (int*)carve((size_t)N * 4);
    int*            psum = (int*)carve(64 * 4);
    uint3*          rec = (uint3*)carve((size_t)E * 12);                    // 9.6 MB
    float*          gst = (float*)carve(256 * 4);
    float*          h   = (float*)xwc;   // reuse: xwc dead after last agg pass

    hipMemsetAsync(deg, 0, (size_t)N * 4, stream);
    hipMemsetAsync(gst, 0, 256 * 4, stream);

    transpose_w_kernel<<<(NK * CIN * COUT) / 256, 256, 0, stream>>>(w, wt);

    // CSR build
    const int nScan = (N + 1023) / 1024;            // 49 blocks
    hist_kernel<<<(E + 255) / 256, 256, 0, stream>>>(ei, deg, E);
    scanA_kernel<<<nScan, 1024, 0, stream>>>(deg, psum, N);
    scanB_kernel<<<1, 64, 0, stream>>>(psum, nScan, off, N);
    scanC_kernel<<<nScan, 1024, 0, stream>>>(deg, psum, off, cur, N);
    scatter_kernel<<<(E + 255) / 256, 256, 0, stream>>>(ei, ea, cur, rec, E);

    const int ggrid = (N + 127) / 128;
    const int agrid = (N * 64 + 255) / 256;
    for (int slab = 0; slab < 4; ++slab) {
        gemm_xw_kernel<<<ggrid, 256, 0, stream>>>(x, wt, xwc, N, slab * SLABK);
        agg_kernel<<<agrid, 256, 0, stream>>>(rec, off, xwc, agg, N, slab);
    }

    node_kernel<<<(N + 63) / 64, 256, 0, stream>>>(x, agg, deg, root, bias, h, gst, N);

    stats_kernel<<<1, 64, 0, stream>>>(gamma, beta, gst, N);

    initpool_kernel<<<(out_size + 255) / 256, 256, 0, stream>>>((unsigned*)d_out, out_size);

    pool_kernel<<<((size_t)N * COUT + 255) / 256, 256, 0, stream>>>(
        h, pos, batch, gst, (unsigned*)d_out, N);

    decode_kernel<<<(out_size + 255) / 256, 256, 0, stream>>>((unsigned*)d_out, out_size);
}